// Round 5
// baseline (316.096 us; speedup 1.0000x reference)
//
#include <hip/hip_runtime.h>
#include <hip/hip_bf16.h>

// SRU: T=4096 B=8 D=H=512, two layers.
// Per layer: bf16 MFMA GEMM 256^2 8-wave (A via swizzled LDS, B direct global->reg dual-bank,
// depth-2 counted-vmcnt pipeline) -> chunked parallel linear scan -> highway epilogue.

#define T_DIM 4096
#define B_DIM 8
#define H_DIM 512
#define M_DIM (T_DIM * B_DIM)   // 32768 rows
#define N3H 1536                // 3*H
#define K_DIM 512
#define NKT (K_DIM / 64)        // 8 K-tiles
#define NCHUNK 512
#define CLEN (T_DIM / NCHUNK)   // 8
#define NCHAIN (B_DIM * H_DIM)  // 4096
#define NGRP 32
#define GLEN (NCHUNK / NGRP)    // 16

typedef __attribute__((ext_vector_type(8))) short s16x8;   // 8 bf16 (4 VGPRs)
typedef __attribute__((ext_vector_type(4))) float f32x4;
typedef unsigned short ushort_t;
typedef unsigned int uint_t;

__device__ __forceinline__ float bf2f(ushort_t u) {
    return __uint_as_float(((uint_t)u) << 16);
}
__device__ __forceinline__ ushort_t f2bf(float f) {
    uint_t u = __float_as_uint(f);
    u += 0x7FFFu + ((u >> 16) & 1u);   // RNE
    return (ushort_t)(u >> 16);
}
__device__ __forceinline__ float sigm(float z) {
    return 1.0f / (1.0f + __expf(-z));
}
__device__ __forceinline__ float tanh_fast(float z) {
    float e = __expf(2.0f * z);
    return (e - 1.0f) / (e + 1.0f);
}

// ---------------- fused fp32 -> bf16 convert for x, W0, W1 ----------------
#define XF4 (M_DIM * K_DIM / 4)          // 4194304 float4
#define WF4 (N3H * K_DIM / 4)            // 196608 float4
__global__ void cvt_all(const float* __restrict__ x, const float* __restrict__ w0,
                        const float* __restrict__ w1, ushort_t* __restrict__ xb,
                        ushort_t* __restrict__ w0b, ushort_t* __restrict__ w1b) {
    int i = blockIdx.x * blockDim.x + threadIdx.x;
    const float* src; ushort_t* dst; int idx;
    if (i < XF4) { src = x; dst = xb; idx = i; }
    else if (i < XF4 + WF4) { src = w0; dst = w0b; idx = i - XF4; }
    else if (i < XF4 + 2 * WF4) { src = w1; dst = w1b; idx = i - XF4 - WF4; }
    else return;
    float4 v = reinterpret_cast<const float4*>(src)[idx];
    ushort4 o;
    o.x = f2bf(v.x); o.y = f2bf(v.y); o.z = f2bf(v.z); o.w = f2bf(v.w);
    reinterpret_cast<ushort4*>(dst)[idx] = o;
}

// ---------------- bf16 GEMM 256x256 tile, BK=64, 8 waves (2Mx4N) ----------------
// C[M][N] = A[M][K] * B[N][K]^T (row-major, K contiguous), C written bf16.
// A: LDS-staged (dbuf 64 KiB), XOR-swizzle byte^=((row&7)<<4) both-sides.
// B: L2-resident (256 KB/panel) -> direct global->VGPR, dual-banked one tile ahead.
// Counted waits: vmcnt(12) steady-state (= B(t+1)[8] + A-stage(t+2)[4] in flight).
__device__ __forceinline__ s16x8 lds_swz_read(const ushort_t* base, int row, int kb) {
    int byte = (row << 7) + (((kb << 1)) ^ ((row & 7) << 4));
    return *reinterpret_cast<const s16x8*>(reinterpret_cast<const char*>(base) + byte);
}

__global__ __launch_bounds__(512, 2) void gemm_bt256(const ushort_t* __restrict__ A,
                                                     const ushort_t* __restrict__ Bm,
                                                     ushort_t* __restrict__ C) {
    __shared__ ushort_t As[2][256 * 64];
    const int ntn = N3H >> 8;                    // 6 col tiles
    const int nwg = gridDim.x;                   // 768 (%8==0)
    const int bid = (int)blockIdx.x;
    const int id = (bid & 7) * (nwg >> 3) + (bid >> 3);   // XCD swizzle (bijective)
    const int tm = id / ntn, tn = id % ntn;
    const int row0 = tm << 8, col0 = tn << 8;
    const int tid = threadIdx.x;
    const int wv = tid >> 6, lane = tid & 63;
    const int wm = wv >> 2, wn = wv & 3;         // 2M x 4N waves; wave tile 128x64
    const int l15 = lane & 15;
    const int kgrp = (lane >> 4) << 3;           // 0,8,16,24

    f32x4 acc[8][4] = {};                        // 8 m-frags x 4 n-frags of 16x16

    const int srow_in_wave = lane >> 3;
    const int sslot = lane & 7;

    // B fragment global base: row (col0 + wn*64 + l15), col kgrp; frag (n,kk2) at
    // +n*16 rows, +t*64 + kk2*32 cols.
    const ushort_t* Bg = Bm + (size_t)(col0 + wn * 64 + l15) * K_DIM + kgrp;

    s16x8 bE[8], bO[8];                          // dual B banks (n*2+kk2)

#define LOADB(bank_, t_)                                                                 \
    {                                                                                    \
        _Pragma("unroll")                                                                \
        for (int n = 0; n < 4; ++n)                                                      \
            _Pragma("unroll")                                                            \
            for (int kk2 = 0; kk2 < 2; ++kk2)                                            \
                bank_[n * 2 + kk2] = *reinterpret_cast<const s16x8*>(                    \
                    Bg + (size_t)(n * 16) * K_DIM + (t_) * 64 + kk2 * 32);               \
    }

#define STAGE_A(buf_, t_)                                                                \
    {                                                                                    \
        const int k0s = (t_) * 64;                                                       \
        _Pragma("unroll")                                                                \
        for (int j = 0; j < 4; ++j) {                                                    \
            const int rl = j * 64 + wv * 8;                                              \
            const int rme = rl + srow_in_wave;                                           \
            const int sl = sslot ^ (rme & 7);   /* inverse swizzle on source */          \
            const ushort_t* ga = A + (size_t)(row0 + rme) * K_DIM + k0s + (sl << 3);     \
            __builtin_amdgcn_global_load_lds(                                            \
                (const __attribute__((address_space(1))) void*)ga,                       \
                (__attribute__((address_space(3))) void*)&As[buf_][rl * 64], 16, 0, 0);  \
        }                                                                                \
    }

#define COMPUTE(Ab_, bk_)                                                                \
    {                                                                                    \
        s16x8 af[4][2];                                                                  \
        _Pragma("unroll")                                                                \
        for (int m = 0; m < 4; ++m)                                                      \
            _Pragma("unroll")                                                            \
            for (int kk2 = 0; kk2 < 2; ++kk2)                                            \
                af[m][kk2] = lds_swz_read(Ab_, wm * 128 + m * 16 + l15, kk2 * 32 + kgrp);\
        _Pragma("unroll")                                                                \
        for (int m = 0; m < 4; ++m)                                                      \
            _Pragma("unroll")                                                            \
            for (int n = 0; n < 4; ++n)                                                  \
                _Pragma("unroll")                                                        \
                for (int kk2 = 0; kk2 < 2; ++kk2)                                        \
                    acc[m][n] = __builtin_amdgcn_mfma_f32_16x16x32_bf16(                 \
                        af[m][kk2], bk_[n * 2 + kk2], acc[m][n], 0, 0, 0);               \
        _Pragma("unroll")                                                                \
        for (int m = 0; m < 4; ++m)                                                      \
            _Pragma("unroll")                                                            \
            for (int kk2 = 0; kk2 < 2; ++kk2)                                            \
                af[m][kk2] = lds_swz_read(Ab_, wm * 128 + (4 + m) * 16 + l15,            \
                                          kk2 * 32 + kgrp);                              \
        _Pragma("unroll")                                                                \
        for (int m = 0; m < 4; ++m)                                                      \
            _Pragma("unroll")                                                            \
            for (int n = 0; n < 4; ++n)                                                  \
                _Pragma("unroll")                                                        \
                for (int kk2 = 0; kk2 < 2; ++kk2)                                        \
                    acc[4 + m][n] = __builtin_amdgcn_mfma_f32_16x16x32_bf16(             \
                        af[m][kk2], bk_[n * 2 + kk2], acc[4 + m][n], 0, 0, 0);           \
    }

#define TILE_BODY(t_, buf_, bkC_, bkN_)                                                  \
    {                                                                                    \
        if ((t_) + 1 < NKT) LOADB(bkN_, (t_) + 1);                                       \
        __builtin_amdgcn_s_setprio(1);                                                   \
        COMPUTE(&As[buf_][0], bkC_);                                                     \
        __builtin_amdgcn_s_setprio(0);                                                   \
        __builtin_amdgcn_s_barrier(); /* all waves done reading As[buf_] */              \
        if ((t_) + 2 < NKT) {                                                            \
            STAGE_A(buf_, (t_) + 2);                                                     \
            asm volatile("s_waitcnt vmcnt(12)" ::: "memory"); /* A(t+1) landed */        \
            __builtin_amdgcn_s_barrier();                                                \
        } else if ((t_) + 1 < NKT) {                                                     \
            asm volatile("s_waitcnt vmcnt(8)" ::: "memory");  /* A(t+1) landed */        \
            __builtin_amdgcn_s_barrier();                                                \
        }                                                                                \
    }

    // prologue: stage A tiles 0,1; load B bank for tile 0; counted wait for A(0)
    STAGE_A(0, 0);
    STAGE_A(1, 1);
    LOADB(bE, 0);
    asm volatile("s_waitcnt vmcnt(12)" ::: "memory");   // A(0) landed; A(1)+B(0) in flight
    __builtin_amdgcn_s_barrier();

#pragma unroll
    for (int tp = 0; tp < NKT / 2; ++tp) {
        TILE_BODY(tp * 2, 0, bE, bO);
        TILE_BODY(tp * 2 + 1, 1, bO, bE);
    }
#undef TILE_BODY
#undef COMPUTE
#undef STAGE_A
#undef LOADB

    // epilogue: C/D layout col=lane&15, row=(lane>>4)*4+v (m89-verified)
    const int crow = (lane >> 4) << 2;
#pragma unroll
    for (int m = 0; m < 8; ++m)
#pragma unroll
        for (int n = 0; n < 4; ++n)
#pragma unroll
            for (int v = 0; v < 4; ++v)
                C[(size_t)(row0 + wm * 128 + m * 16 + crow + v) * N3H + (col0 + wn * 64 + n * 16 + l15)] =
                    f2bf(acc[m][n][v]);
}

// ---------------- scan pass A: per-chunk summaries (A=prod f, B=local c) ----------------
__global__ void scan_summary(const ushort_t* __restrict__ U, const float* __restrict__ bias,
                             float* __restrict__ Sa, float* __restrict__ Sb) {
    const int b = blockIdx.x / NCHUNK;
    const int chunk = blockIdx.x % NCHUNK;
    const int h = threadIdx.x << 2;
    float fb[4];
#pragma unroll
    for (int j = 0; j < 4; ++j) fb[j] = bias[h + j];
    float Aa[4] = {1.f, 1.f, 1.f, 1.f};
    float Bb[4] = {0.f, 0.f, 0.f, 0.f};
    const ushort_t* rp = U + ((size_t)(chunk * CLEN) * B_DIM + b) * N3H + h;
    ushort4 xt = *reinterpret_cast<const ushort4*>(rp);
    ushort4 fp = *reinterpret_cast<const ushort4*>(rp + H_DIM);
#pragma unroll
    for (int s = 0; s < CLEN; ++s) {
        ushort4 xt_n, fp_n;
        if (s + 1 < CLEN) {
            rp += (size_t)B_DIM * N3H;
            xt_n = *reinterpret_cast<const ushort4*>(rp);
            fp_n = *reinterpret_cast<const ushort4*>(rp + H_DIM);
        }
        float xs[4] = {bf2f(xt.x), bf2f(xt.y), bf2f(xt.z), bf2f(xt.w)};
        float fs[4] = {bf2f(fp.x), bf2f(fp.y), bf2f(fp.z), bf2f(fp.w)};
#pragma unroll
        for (int j = 0; j < 4; ++j) {
            float f = sigm(fs[j] + fb[j]);
            Aa[j] *= f;
            Bb[j] = f * Bb[j] + (1.f - f) * xs[j];
        }
        xt = xt_n; fp = fp_n;
    }
    const int cb = chunk * NCHAIN + b * H_DIM + h;
#pragma unroll
    for (int j = 0; j < 4; ++j) { Sa[cb + j] = Aa[j]; Sb[cb + j] = Bb[j]; }
}

// ---------------- scan pass B1: per-group local exclusive prefixes (in-place) + group summaries ----------------
__global__ void scan_fixup1(float* Sa, float* Sb, float* __restrict__ Ga, float* __restrict__ Gb) {
    const int idx = blockIdx.x * blockDim.x + threadIdx.x;   // NGRP*4096
    const int chain = idx & (NCHAIN - 1);
    const int g = idx >> 12;
    float A = 1.f, B = 0.f;
#pragma unroll
    for (int i = 0; i < GLEN; ++i) {
        const size_t off = (size_t)(g * GLEN + i) * NCHAIN + chain;
        float a = Sa[off], b = Sb[off];
        Sa[off] = A; Sb[off] = B;       // exclusive prefix (read-before-write, thread-owned)
        B = a * B + b;
        A = a * A;
    }
    Ga[g * NCHAIN + chain] = A;
    Gb[g * NCHAIN + chain] = B;
}

// ---------------- scan pass B2: scan group summaries -> group-entry states ----------------
__global__ void scan_fixup2(const float* __restrict__ Ga, const float* __restrict__ Gb,
                            float* __restrict__ Eg, float* __restrict__ clast) {
    const int chain = blockIdx.x * blockDim.x + threadIdx.x;  // 4096
    float c = 0.f;
#pragma unroll
    for (int g = 0; g < NGRP; ++g) {
        Eg[g * NCHAIN + chain] = c;
        c = Ga[g * NCHAIN + chain] * c + Gb[g * NCHAIN + chain];
    }
    if (clast) clast[chain] = c;   // chain = b*H + h -> [B][H]
}

// ---------------- scan pass C: apply with reconstructed entry c + highway epilogue ----------------
template <bool IN_BF16, bool OUT_BF16>
__global__ void scan_apply(const ushort_t* __restrict__ U, const float* __restrict__ bias,
                           const float* __restrict__ Sa, const float* __restrict__ Sb,
                           const float* __restrict__ Eg,
                           const void* __restrict__ xin, void* __restrict__ hout) {
    const int b = blockIdx.x / NCHUNK;
    const int chunk = blockIdx.x % NCHUNK;
    const int h = threadIdx.x << 2;
    const int cb = chunk * NCHAIN + b * H_DIM + h;
    const int eb = (chunk >> 4) * NCHAIN + b * H_DIM + h;   // group (GLEN=16) of this chunk
    float cc[4], fb[4], rb[4];
    float4 la = *reinterpret_cast<const float4*>(&Sa[cb]);
    float4 lb = *reinterpret_cast<const float4*>(&Sb[cb]);
    float4 eg = *reinterpret_cast<const float4*>(&Eg[eb]);
    cc[0] = lb.x + la.x * eg.x; cc[1] = lb.y + la.y * eg.y;
    cc[2] = lb.z + la.z * eg.z; cc[3] = lb.w + la.w * eg.w;
#pragma unroll
    for (int j = 0; j < 4; ++j) {
        fb[j] = bias[h + j];
        rb[j] = bias[H_DIM + h + j];
    }
    size_t row = (size_t)(chunk * CLEN) * B_DIM + b;
    const ushort_t* rp = U + row * N3H + h;
    size_t xoff = row * H_DIM + h;

    ushort4 xt = *reinterpret_cast<const ushort4*>(rp);
    ushort4 fp = *reinterpret_cast<const ushort4*>(rp + H_DIM);
    ushort4 rr = *reinterpret_cast<const ushort4*>(rp + 2 * H_DIM);
    float xv[4];
    if (IN_BF16) {
        ushort4 xi = *reinterpret_cast<const ushort4*>((const ushort_t*)xin + xoff);
        xv[0] = bf2f(xi.x); xv[1] = bf2f(xi.y); xv[2] = bf2f(xi.z); xv[3] = bf2f(xi.w);
    } else {
        float4 xi = *reinterpret_cast<const float4*>((const float*)xin + xoff);
        xv[0] = xi.x; xv[1] = xi.y; xv[2] = xi.z; xv[3] = xi.w;
    }

#pragma unroll
    for (int s = 0; s < CLEN; ++s) {
        ushort4 xt_n, fp_n, rr_n;
        float xv_n[4];
        if (s + 1 < CLEN) {
            rp += (size_t)B_DIM * N3H;
            xt_n = *reinterpret_cast<const ushort4*>(rp);
            fp_n = *reinterpret_cast<const ushort4*>(rp + H_DIM);
            rr_n = *reinterpret_cast<const ushort4*>(rp + 2 * H_DIM);
            size_t xo2 = xoff + (size_t)B_DIM * H_DIM;
            if (IN_BF16) {
                ushort4 xi = *reinterpret_cast<const ushort4*>((const ushort_t*)xin + xo2);
                xv_n[0] = bf2f(xi.x); xv_n[1] = bf2f(xi.y); xv_n[2] = bf2f(xi.z); xv_n[3] = bf2f(xi.w);
            } else {
                float4 xi = *reinterpret_cast<const float4*>((const float*)xin + xo2);
                xv_n[0] = xi.x; xv_n[1] = xi.y; xv_n[2] = xi.z; xv_n[3] = xi.w;
            }
        }
        float xts[4] = {bf2f(xt.x), bf2f(xt.y), bf2f(xt.z), bf2f(xt.w)};
        float fps[4] = {bf2f(fp.x), bf2f(fp.y), bf2f(fp.z), bf2f(fp.w)};
        float rps[4] = {bf2f(rr.x), bf2f(rr.y), bf2f(rr.z), bf2f(rr.w)};
        float hv[4];
#pragma unroll
        for (int j = 0; j < 4; ++j) {
            float f = sigm(fps[j] + fb[j]);
            cc[j] = f * cc[j] + (1.f - f) * xts[j];
            float r = sigm(rps[j] + rb[j]);
            hv[j] = r * tanh_fast(cc[j]) + (1.f - r) * xv[j];
        }
        if (OUT_BF16) {
            ushort4 o;
            o.x = f2bf(hv[0]); o.y = f2bf(hv[1]); o.z = f2bf(hv[2]); o.w = f2bf(hv[3]);
            *reinterpret_cast<ushort4*>((ushort_t*)hout + xoff) = o;
        } else {
            float4 o;
            o.x = hv[0]; o.y = hv[1]; o.z = hv[2]; o.w = hv[3];
            *reinterpret_cast<float4*>((float*)hout + xoff) = o;
        }
        xoff += (size_t)B_DIM * H_DIM;
        xt = xt_n; fp = fp_n; rr = rr_n;
        xv[0] = xv_n[0]; xv[1] = xv_n[1]; xv[2] = xv_n[2]; xv[3] = xv_n[3];
    }
}

extern "C" void kernel_launch(void* const* d_in, const int* in_sizes, int n_in,
                              void* d_out, int out_size, void* d_ws, size_t ws_size,
                              hipStream_t stream) {
    (void)in_sizes; (void)n_in; (void)out_size; (void)ws_size;
    const float* x  = (const float*)d_in[0];   // [T,B,512]
    const float* W0 = (const float*)d_in[1];   // [1536,512]
    const float* b0 = (const float*)d_in[2];   // [1024]
    const float* W1 = (const float*)d_in[3];   // [1536,512]
    const float* b1 = (const float*)d_in[4];   // [1024]
    float* out = (float*)d_out;                // h [T,B,512] fp32, then c_last [B,512] fp32

    // ws layout (bytes); total 163 MiB.
    // [0,32M): xb (bf16 x) -- dead after GEMM1; Sa/Sb/Ga/Gb/Eg alias here afterwards
    char* ws = (char*)d_ws;
    ushort_t* xb  = (ushort_t*)(ws);
    float*    Sa  = (float*)(ws);                 // 8 MiB
    float*    Sb  = (float*)(ws + 8388608);       // 8 MiB
    float*    Ga  = (float*)(ws + 16777216);      // 512 KiB
    float*    Gb  = (float*)(ws + 17301504);      // 512 KiB
    float*    Eg  = (float*)(ws + 17825792);      // 512 KiB
    ushort_t* h1  = (ushort_t*)(ws + 33554432);   // 32 MiB
    ushort_t* W0b = (ushort_t*)(ws + 67108864);   // 1.5 MiB
    ushort_t* W1b = (ushort_t*)(ws + 68681728);   // 1.5 MiB
    ushort_t* U   = (ushort_t*)(ws + 70254592);   // 96 MiB

    const int cvt_total = XF4 + 2 * WF4;
    cvt_all<<<(cvt_total + 255) / 256, 256, 0, stream>>>(x, W0, W1, xb, W0b, W1b);

    const int gemm_grid = (M_DIM / 256) * (N3H / 256);   // 768 (%8==0)
    const int scan_grid = B_DIM * NCHUNK;                 // 4096

    // ---- layer 1 ----
    gemm_bt256<<<gemm_grid, 512, 0, stream>>>(xb, W0b, U);
    scan_summary<<<scan_grid, 128, 0, stream>>>(U, b0, Sa, Sb);
    scan_fixup1<<<NGRP * NCHAIN / 256, 256, 0, stream>>>(Sa, Sb, Ga, Gb);
    scan_fixup2<<<NCHAIN / 256, 256, 0, stream>>>(Ga, Gb, Eg, nullptr);
    scan_apply<false, true><<<scan_grid, 128, 0, stream>>>(U, b0, Sa, Sb, Eg, (const void*)x, (void*)h1);

    // ---- layer 2 ----
    gemm_bt256<<<gemm_grid, 512, 0, stream>>>(h1, W1b, U);
    scan_summary<<<scan_grid, 128, 0, stream>>>(U, b1, Sa, Sb);
    scan_fixup1<<<NGRP * NCHAIN / 256, 256, 0, stream>>>(Sa, Sb, Ga, Gb);
    scan_fixup2<<<NCHAIN / 256, 256, 0, stream>>>(Ga, Gb, Eg, out + (size_t)M_DIM * H_DIM);
    scan_apply<true, false><<<scan_grid, 128, 0, stream>>>(U, b1, Sa, Sb, Eg, (const void*)h1, (void*)out);
}

// Round 6
// 283.816 us; speedup vs baseline: 1.1137x; 1.1137x over previous
//
#include <hip/hip_runtime.h>
#include <hip/hip_bf16.h>

// SRU: T=4096 B=8 D=H=512, two layers.
// Per layer: bf16 MFMA GEMM 256^2, 8 waves, m201-style 4-phase/K-tile schedule with
// counted vmcnt (U = in @ W^T) -> chunked parallel linear scan -> highway epilogue.

#define T_DIM 4096
#define B_DIM 8
#define H_DIM 512
#define M_DIM (T_DIM * B_DIM)   // 32768 rows
#define N3H 1536                // 3*H
#define K_DIM 512
#define NKT (K_DIM / 64)        // 8 K-tiles
#define NCHUNK 512
#define CLEN (T_DIM / NCHUNK)   // 8
#define NCHAIN (B_DIM * H_DIM)  // 4096
#define NGRP 32
#define GLEN (NCHUNK / NGRP)    // 16

typedef __attribute__((ext_vector_type(8))) short s16x8;   // 8 bf16 (4 VGPRs)
typedef __attribute__((ext_vector_type(4))) float f32x4;
typedef unsigned short ushort_t;
typedef unsigned int uint_t;

__device__ __forceinline__ float bf2f(ushort_t u) {
    return __uint_as_float(((uint_t)u) << 16);
}
__device__ __forceinline__ ushort_t f2bf(float f) {
    uint_t u = __float_as_uint(f);
    u += 0x7FFFu + ((u >> 16) & 1u);   // RNE
    return (ushort_t)(u >> 16);
}
__device__ __forceinline__ float sigm(float z) {
    return 1.0f / (1.0f + __expf(-z));
}
__device__ __forceinline__ float tanh_fast(float z) {
    float e = __expf(2.0f * z);
    return (e - 1.0f) / (e + 1.0f);
}

// ---------------- fused fp32 -> bf16 convert for x, W0, W1 ----------------
#define XF4 (M_DIM * K_DIM / 4)          // 4194304 float4
#define WF4 (N3H * K_DIM / 4)            // 196608 float4
__global__ void cvt_all(const float* __restrict__ x, const float* __restrict__ w0,
                        const float* __restrict__ w1, ushort_t* __restrict__ xb,
                        ushort_t* __restrict__ w0b, ushort_t* __restrict__ w1b) {
    int i = blockIdx.x * blockDim.x + threadIdx.x;
    const float* src; ushort_t* dst; int idx;
    if (i < XF4) { src = x; dst = xb; idx = i; }
    else if (i < XF4 + WF4) { src = w0; dst = w0b; idx = i - XF4; }
    else if (i < XF4 + 2 * WF4) { src = w1; dst = w1b; idx = i - XF4 - WF4; }
    else return;
    float4 v = reinterpret_cast<const float4*>(src)[idx];
    ushort4 o;
    o.x = f2bf(v.x); o.y = f2bf(v.y); o.z = f2bf(v.z); o.w = f2bf(v.w);
    reinterpret_cast<ushort4*>(dst)[idx] = o;
}

// ---------------- bf16 GEMM 256x256 tile, BK=64, 8 waves (2Mx4N), 4-phase/K-tile ----------------
// C[M][N] = A[M][K] * B[N][K]^T (row-major, K contiguous), C written bf16.
// LDS: [2 dbuf][2 half][128x64] bf16 for A and B = 128 KiB. XOR-swizzle
// byte^=((row&7)<<4) applied both-sides (pre-swizzled global source for
// global_load_lds linear dest + swizzled ds_read).
// Phase p: {ds-read subtile || stage 1 half-tile -> barrier -> lgkmcnt(0) ->
// setprio(1) -> 16 MFMA -> setprio(0) -> barrier}. One counted vmcnt(4)/K-tile.
// Liveness (audited): A halves free after P3 of their tile, B halves after P2.
// Stage schedule: P1:Bh1(u+1), P2:Ah1(u+1), P3:Bh0(u+2), P4:Ah0(u+2).
__device__ __forceinline__ s16x8 lds_swz_read(const ushort_t* base, int row, int kb) {
    int byte = (row << 7) + (((kb << 1)) ^ ((row & 7) << 4));
    return *reinterpret_cast<const s16x8*>(reinterpret_cast<const char*>(base) + byte);
}

__global__ __launch_bounds__(512, 2) void gemm_bt256(const ushort_t* __restrict__ A,
                                                     const ushort_t* __restrict__ Bm,
                                                     ushort_t* __restrict__ C) {
    __shared__ ushort_t As[2][2][128 * 64];
    __shared__ ushort_t Bs[2][2][128 * 64];
    const int ntn = N3H >> 8;                    // 6 col tiles
    const int nwg = gridDim.x;                   // 768 (%8==0)
    const int bid = (int)blockIdx.x;
    const int id = (bid & 7) * (nwg >> 3) + (bid >> 3);   // XCD swizzle (bijective)
    const int tm = id / ntn, tn = id % ntn;
    const int row0 = tm << 8, col0 = tn << 8;
    const int tid = threadIdx.x;
    const int wv = tid >> 6, lane = tid & 63;
    const int wm = wv >> 2, wn = wv & 3;         // 2M x 4N waves; wave tile 128x64
    const int l15 = lane & 15;
    const int kgrp = (lane >> 4) << 3;           // 0,8,16,24

    f32x4 acc[8][4] = {};                        // 8 m-frags x 4 n-frags of 16x16

    const int srw = lane >> 3;                   // row within 8-row wave segment
    const int ssl = lane & 7;                    // 16B slot within 128B row

    // stage one 128x64 half-tile (2 x global_load_lds per thread, inverse-swizzled src)
#define STAGE_H(ARR, GP, BASE0, hh, t_, d_)                                              \
    {                                                                                    \
        _Pragma("unroll")                                                                \
        for (int j = 0; j < 2; ++j) {                                                    \
            const int rl = j * 64 + wv * 8 + srw;                                        \
            const int sl = ssl ^ (rl & 7);                                               \
            const ushort_t* gp_ = (GP) + (size_t)((BASE0) + (hh) * 128 + rl) * K_DIM     \
                                  + (t_) * 64 + (sl << 3);                               \
            __builtin_amdgcn_global_load_lds(                                            \
                (const __attribute__((address_space(1))) void*)gp_,                      \
                (__attribute__((address_space(3))) void*)&ARR[d_][hh][(j * 64 + wv * 8) * 64], \
                16, 0, 0);                                                               \
        }                                                                                \
    }

#define LDA_HALF(mbase_)                                                                 \
    _Pragma("unroll")                                                                    \
    for (int m = 0; m < 4; ++m)                                                          \
        _Pragma("unroll")                                                                \
        for (int kk = 0; kk < 2; ++kk)                                                   \
            af[m][kk] = lds_swz_read(&As[buf][wm][0], (mbase_ + m) * 16 + l15,           \
                                     kk * 32 + kgrp);

#define LDB_PAIR(nbase_)                                                                 \
    _Pragma("unroll")                                                                    \
    for (int n = 0; n < 2; ++n)                                                          \
        _Pragma("unroll")                                                                \
        for (int kk = 0; kk < 2; ++kk)                                                   \
            bfr[(nbase_) + n][kk] = lds_swz_read(&Bs[buf][wn >> 1][0],                   \
                (wn & 1) * 64 + ((nbase_) + n) * 16 + l15, kk * 32 + kgrp);

#define MFMA_Q(mbase_, nbase_)                                                           \
    _Pragma("unroll")                                                                    \
    for (int m = 0; m < 4; ++m)                                                          \
        _Pragma("unroll")                                                                \
        for (int n = 0; n < 2; ++n)                                                      \
            _Pragma("unroll")                                                            \
            for (int kk = 0; kk < 2; ++kk)                                               \
                acc[(mbase_) + m][(nbase_) + n] = __builtin_amdgcn_mfma_f32_16x16x32_bf16( \
                    af[m][kk], bfr[(nbase_) + n][kk], acc[(mbase_) + m][(nbase_) + n],   \
                    0, 0, 0);

    // prologue: issue 6 half-tiles in steady-state order, counted wait for tile 0
    STAGE_H(Bs, Bm, col0, 0, 0, 0);   // Bh0(0)  [as-if P3(-2)]
    STAGE_H(As, A, row0, 0, 0, 0);    // Ah0(0)  [P4(-2)]
    STAGE_H(Bs, Bm, col0, 1, 0, 0);   // Bh1(0)  [P1(-1)]
    STAGE_H(As, A, row0, 1, 0, 0);    // Ah1(0)  [P2(-1)]
    STAGE_H(Bs, Bm, col0, 0, 1, 1);   // Bh0(1)  [P3(-1)]
    STAGE_H(As, A, row0, 0, 1, 1);    // Ah0(1)  [P4(-1)]
    asm volatile("s_waitcnt vmcnt(4)" ::: "memory");   // tile 0 landed; Bh0(1),Ah0(1) in flight
    __builtin_amdgcn_s_barrier();

#pragma unroll
    for (int u = 0; u < NKT; ++u) {
        const int buf = u & 1;
        s16x8 af[4][2], bfr[4][2];

        // ---- P1: A m0-3 (8 ds) + B n0-1 (4 ds) | stage Bh1(u+1) ----
        LDA_HALF(0);
        LDB_PAIR(0);
        if (u + 1 < NKT) { STAGE_H(Bs, Bm, col0, 1, u + 1, buf ^ 1); }
        __builtin_amdgcn_s_barrier();
        asm volatile("s_waitcnt lgkmcnt(0)" ::: "memory");
        __builtin_amdgcn_s_setprio(1);
        MFMA_Q(0, 0);
        __builtin_amdgcn_s_setprio(0);
        __builtin_amdgcn_s_barrier();

        // ---- P2: B n2-3 (4 ds) | stage Ah1(u+1) ----
        LDB_PAIR(2);
        if (u + 1 < NKT) { STAGE_H(As, A, row0, 1, u + 1, buf ^ 1); }
        __builtin_amdgcn_s_barrier();
        asm volatile("s_waitcnt lgkmcnt(0)" ::: "memory");
        __builtin_amdgcn_s_setprio(1);
        MFMA_Q(0, 2);
        __builtin_amdgcn_s_setprio(0);
        __builtin_amdgcn_s_barrier();

        // ---- P3: A m4-7 (8 ds) | stage Bh0(u+2) ----
        LDA_HALF(4);
        if (u + 2 < NKT) { STAGE_H(Bs, Bm, col0, 0, u + 2, buf); }
        __builtin_amdgcn_s_barrier();
        asm volatile("s_waitcnt lgkmcnt(0)" ::: "memory");
        __builtin_amdgcn_s_setprio(1);
        MFMA_Q(4, 0);
        __builtin_amdgcn_s_setprio(0);
        __builtin_amdgcn_s_barrier();

        // ---- P4: no ds | stage Ah0(u+2) | counted vmcnt for tile u+1 ----
        if (u + 2 < NKT) { STAGE_H(As, A, row0, 0, u + 2, buf); }
        __builtin_amdgcn_s_barrier();
        __builtin_amdgcn_s_setprio(1);
        MFMA_Q(4, 2);
        __builtin_amdgcn_s_setprio(0);
        if (u + 2 < NKT)      { asm volatile("s_waitcnt vmcnt(4)" ::: "memory"); }
        else if (u + 1 < NKT) { asm volatile("s_waitcnt vmcnt(0)" ::: "memory"); }
        __builtin_amdgcn_s_barrier();
    }
#undef MFMA_Q
#undef LDB_PAIR
#undef LDA_HALF
#undef STAGE_H

    // epilogue: C/D layout col=lane&15, row=(lane>>4)*4+v (m89-verified)
    const int crow = (lane >> 4) << 2;
#pragma unroll
    for (int m = 0; m < 8; ++m)
#pragma unroll
        for (int n = 0; n < 4; ++n)
#pragma unroll
            for (int v = 0; v < 4; ++v)
                C[(size_t)(row0 + wm * 128 + m * 16 + crow + v) * N3H + (col0 + wn * 64 + n * 16 + l15)] =
                    f2bf(acc[m][n][v]);
}

// ---------------- scan pass A: per-chunk summaries (A=prod f, B=local c) ----------------
__global__ void scan_summary(const ushort_t* __restrict__ U, const float* __restrict__ bias,
                             float* __restrict__ Sa, float* __restrict__ Sb) {
    const int b = blockIdx.x / NCHUNK;
    const int chunk = blockIdx.x % NCHUNK;
    const int h = threadIdx.x << 2;
    float fb[4];
#pragma unroll
    for (int j = 0; j < 4; ++j) fb[j] = bias[h + j];
    float Aa[4] = {1.f, 1.f, 1.f, 1.f};
    float Bb[4] = {0.f, 0.f, 0.f, 0.f};
    const ushort_t* rp = U + ((size_t)(chunk * CLEN) * B_DIM + b) * N3H + h;
    ushort4 xt = *reinterpret_cast<const ushort4*>(rp);
    ushort4 fp = *reinterpret_cast<const ushort4*>(rp + H_DIM);
#pragma unroll
    for (int s = 0; s < CLEN; ++s) {
        ushort4 xt_n, fp_n;
        if (s + 1 < CLEN) {
            rp += (size_t)B_DIM * N3H;
            xt_n = *reinterpret_cast<const ushort4*>(rp);
            fp_n = *reinterpret_cast<const ushort4*>(rp + H_DIM);
        }
        float xs[4] = {bf2f(xt.x), bf2f(xt.y), bf2f(xt.z), bf2f(xt.w)};
        float fs[4] = {bf2f(fp.x), bf2f(fp.y), bf2f(fp.z), bf2f(fp.w)};
#pragma unroll
        for (int j = 0; j < 4; ++j) {
            float f = sigm(fs[j] + fb[j]);
            Aa[j] *= f;
            Bb[j] = f * Bb[j] + (1.f - f) * xs[j];
        }
        xt = xt_n; fp = fp_n;
    }
    const int cb = chunk * NCHAIN + b * H_DIM + h;
#pragma unroll
    for (int j = 0; j < 4; ++j) { Sa[cb + j] = Aa[j]; Sb[cb + j] = Bb[j]; }
}

// ---------------- scan pass B1: per-group local exclusive prefixes (in-place) + group summaries ----------------
__global__ void scan_fixup1(float* Sa, float* Sb, float* __restrict__ Ga, float* __restrict__ Gb) {
    const int idx = blockIdx.x * blockDim.x + threadIdx.x;   // NGRP*4096
    const int chain = idx & (NCHAIN - 1);
    const int g = idx >> 12;
    float A = 1.f, B = 0.f;
#pragma unroll
    for (int i = 0; i < GLEN; ++i) {
        const size_t off = (size_t)(g * GLEN + i) * NCHAIN + chain;
        float a = Sa[off], b = Sb[off];
        Sa[off] = A; Sb[off] = B;       // exclusive prefix (read-before-write, thread-owned)
        B = a * B + b;
        A = a * A;
    }
    Ga[g * NCHAIN + chain] = A;
    Gb[g * NCHAIN + chain] = B;
}

// ---------------- scan pass B2: scan group summaries -> group-entry states ----------------
__global__ void scan_fixup2(const float* __restrict__ Ga, const float* __restrict__ Gb,
                            float* __restrict__ Eg, float* __restrict__ clast) {
    const int chain = blockIdx.x * blockDim.x + threadIdx.x;  // 4096
    float c = 0.f;
#pragma unroll
    for (int g = 0; g < NGRP; ++g) {
        Eg[g * NCHAIN + chain] = c;
        c = Ga[g * NCHAIN + chain] * c + Gb[g * NCHAIN + chain];
    }
    if (clast) clast[chain] = c;   // chain = b*H + h -> [B][H]
}

// ---------------- scan pass C: apply with reconstructed entry c + highway epilogue ----------------
template <bool IN_BF16, bool OUT_BF16>
__global__ void scan_apply(const ushort_t* __restrict__ U, const float* __restrict__ bias,
                           const float* __restrict__ Sa, const float* __restrict__ Sb,
                           const float* __restrict__ Eg,
                           const void* __restrict__ xin, void* __restrict__ hout) {
    const int b = blockIdx.x / NCHUNK;
    const int chunk = blockIdx.x % NCHUNK;
    const int h = threadIdx.x << 2;
    const int cb = chunk * NCHAIN + b * H_DIM + h;
    const int eb = (chunk >> 4) * NCHAIN + b * H_DIM + h;   // group (GLEN=16) of this chunk
    float cc[4], fb[4], rb[4];
    float4 la = *reinterpret_cast<const float4*>(&Sa[cb]);
    float4 lb = *reinterpret_cast<const float4*>(&Sb[cb]);
    float4 eg = *reinterpret_cast<const float4*>(&Eg[eb]);
    cc[0] = lb.x + la.x * eg.x; cc[1] = lb.y + la.y * eg.y;
    cc[2] = lb.z + la.z * eg.z; cc[3] = lb.w + la.w * eg.w;
#pragma unroll
    for (int j = 0; j < 4; ++j) {
        fb[j] = bias[h + j];
        rb[j] = bias[H_DIM + h + j];
    }
    size_t row = (size_t)(chunk * CLEN) * B_DIM + b;
    const ushort_t* rp = U + row * N3H + h;
    size_t xoff = row * H_DIM + h;

    ushort4 xt = *reinterpret_cast<const ushort4*>(rp);
    ushort4 fp = *reinterpret_cast<const ushort4*>(rp + H_DIM);
    ushort4 rr = *reinterpret_cast<const ushort4*>(rp + 2 * H_DIM);
    float xv[4];
    if (IN_BF16) {
        ushort4 xi = *reinterpret_cast<const ushort4*>((const ushort_t*)xin + xoff);
        xv[0] = bf2f(xi.x); xv[1] = bf2f(xi.y); xv[2] = bf2f(xi.z); xv[3] = bf2f(xi.w);
    } else {
        float4 xi = *reinterpret_cast<const float4*>((const float*)xin + xoff);
        xv[0] = xi.x; xv[1] = xi.y; xv[2] = xi.z; xv[3] = xi.w;
    }

#pragma unroll
    for (int s = 0; s < CLEN; ++s) {
        ushort4 xt_n, fp_n, rr_n;
        float xv_n[4];
        if (s + 1 < CLEN) {
            rp += (size_t)B_DIM * N3H;
            xt_n = *reinterpret_cast<const ushort4*>(rp);
            fp_n = *reinterpret_cast<const ushort4*>(rp + H_DIM);
            rr_n = *reinterpret_cast<const ushort4*>(rp + 2 * H_DIM);
            size_t xo2 = xoff + (size_t)B_DIM * H_DIM;
            if (IN_BF16) {
                ushort4 xi = *reinterpret_cast<const ushort4*>((const ushort_t*)xin + xo2);
                xv_n[0] = bf2f(xi.x); xv_n[1] = bf2f(xi.y); xv_n[2] = bf2f(xi.z); xv_n[3] = bf2f(xi.w);
            } else {
                float4 xi = *reinterpret_cast<const float4*>((const float*)xin + xo2);
                xv_n[0] = xi.x; xv_n[1] = xi.y; xv_n[2] = xi.z; xv_n[3] = xi.w;
            }
        }
        float xts[4] = {bf2f(xt.x), bf2f(xt.y), bf2f(xt.z), bf2f(xt.w)};
        float fps[4] = {bf2f(fp.x), bf2f(fp.y), bf2f(fp.z), bf2f(fp.w)};
        float rps[4] = {bf2f(rr.x), bf2f(rr.y), bf2f(rr.z), bf2f(rr.w)};
        float hv[4];
#pragma unroll
        for (int j = 0; j < 4; ++j) {
            float f = sigm(fps[j] + fb[j]);
            cc[j] = f * cc[j] + (1.f - f) * xts[j];
            float r = sigm(rps[j] + rb[j]);
            hv[j] = r * tanh_fast(cc[j]) + (1.f - r) * xv[j];
        }
        if (OUT_BF16) {
            ushort4 o;
            o.x = f2bf(hv[0]); o.y = f2bf(hv[1]); o.z = f2bf(hv[2]); o.w = f2bf(hv[3]);
            *reinterpret_cast<ushort4*>((ushort_t*)hout + xoff) = o;
        } else {
            float4 o;
            o.x = hv[0]; o.y = hv[1]; o.z = hv[2]; o.w = hv[3];
            *reinterpret_cast<float4*>((float*)hout + xoff) = o;
        }
        xoff += (size_t)B_DIM * H_DIM;
        xt = xt_n; fp = fp_n; rr = rr_n;
        xv[0] = xv_n[0]; xv[1] = xv_n[1]; xv[2] = xv_n[2]; xv[3] = xv_n[3];
    }
}

extern "C" void kernel_launch(void* const* d_in, const int* in_sizes, int n_in,
                              void* d_out, int out_size, void* d_ws, size_t ws_size,
                              hipStream_t stream) {
    (void)in_sizes; (void)n_in; (void)out_size; (void)ws_size;
    const float* x  = (const float*)d_in[0];   // [T,B,512]
    const float* W0 = (const float*)d_in[1];   // [1536,512]
    const float* b0 = (const float*)d_in[2];   // [1024]
    const float* W1 = (const float*)d_in[3];   // [1536,512]
    const float* b1 = (const float*)d_in[4];   // [1024]
    float* out = (float*)d_out;                // h [T,B,512] fp32, then c_last [B,512] fp32

    // ws layout (bytes); total 163 MiB.
    // [0,32M): xb (bf16 x) -- dead after GEMM1; Sa/Sb/Ga/Gb/Eg alias here afterwards
    char* ws = (char*)d_ws;
    ushort_t* xb  = (ushort_t*)(ws);
    float*    Sa  = (float*)(ws);                 // 8 MiB
    float*    Sb  = (float*)(ws + 8388608);       // 8 MiB
    float*    Ga  = (float*)(ws + 16777216);      // 512 KiB
    float*    Gb  = (float*)(ws + 17301504);      // 512 KiB
    float*    Eg  = (float*)(ws + 17825792);      // 512 KiB
    ushort_t* h1  = (ushort_t*)(ws + 33554432);   // 32 MiB
    ushort_t* W0b = (ushort_t*)(ws + 67108864);   // 1.5 MiB
    ushort_t* W1b = (ushort_t*)(ws + 68681728);   // 1.5 MiB
    ushort_t* U   = (ushort_t*)(ws + 70254592);   // 96 MiB

    const int cvt_total = XF4 + 2 * WF4;
    cvt_all<<<(cvt_total + 255) / 256, 256, 0, stream>>>(x, W0, W1, xb, W0b, W1b);

    const int gemm_grid = (M_DIM / 256) * (N3H / 256);   // 768 (%8==0)
    const int scan_grid = B_DIM * NCHUNK;                 // 4096

    // ---- layer 1 ----
    gemm_bt256<<<gemm_grid, 512, 0, stream>>>(xb, W0b, U);
    scan_summary<<<scan_grid, 128, 0, stream>>>(U, b0, Sa, Sb);
    scan_fixup1<<<NGRP * NCHAIN / 256, 256, 0, stream>>>(Sa, Sb, Ga, Gb);
    scan_fixup2<<<NCHAIN / 256, 256, 0, stream>>>(Ga, Gb, Eg, nullptr);
    scan_apply<false, true><<<scan_grid, 128, 0, stream>>>(U, b0, Sa, Sb, Eg, (const void*)x, (void*)h1);

    // ---- layer 2 ----
    gemm_bt256<<<gemm_grid, 512, 0, stream>>>(h1, W1b, U);
    scan_summary<<<scan_grid, 128, 0, stream>>>(U, b1, Sa, Sb);
    scan_fixup1<<<NGRP * NCHAIN / 256, 256, 0, stream>>>(Sa, Sb, Ga, Gb);
    scan_fixup2<<<NCHAIN / 256, 256, 0, stream>>>(Ga, Gb, Eg, out + (size_t)M_DIM * H_DIM);
    scan_apply<true, false><<<scan_grid, 128, 0, stream>>>(U, b1, Sa, Sb, Eg, (const void*)h1, (void*)out);
}